// Round 5
// baseline (531.589 us; speedup 1.0000x reference)
//
#include <hip/hip_runtime.h>
#include <hip/hip_bf16.h>

using bf16 = __hip_bfloat16;
typedef __bf16 v8bf __attribute__((ext_vector_type(8)));
typedef float v4f __attribute__((ext_vector_type(4)));

#define H_ 1024
#define A_ 16
#define O_ 4
#define B_ 4096
#define P_ 2048
#define EPS_ 1e-5f

// async global->LDS, 16B per lane; lds pointer must be wave-uniform base.
__device__ __forceinline__ void gl_lds16(const void* g, void* l) {
    __builtin_amdgcn_global_load_lds(
        (const __attribute__((address_space(1))) void*)g,
        (__attribute__((address_space(3))) void*)l, 16, 0, 0);
}

// ---- gather selected rows of X,X1 -> XX (bf16); tail blocks do b12=b1+b2 --
__global__ __launch_bounds__(256) void gather_bias_k(const float* __restrict__ X,
                                                     const float* __restrict__ X1,
                                                     const int* __restrict__ pos,
                                                     bf16* __restrict__ XX,
                                                     const float* __restrict__ b1,
                                                     const float* __restrict__ b2,
                                                     float* __restrict__ b12) {
    if (blockIdx.x >= P_) {
        int i = (blockIdx.x - P_) * 256 + threadIdx.x;
        if (i < A_ * H_) b12[i] = b1[i] + b2[i];
        return;
    }
    int p = blockIdx.x;
    int row = pos[p];
    const float4* x  = (const float4*)(X  + (size_t)row * H_);
    const float4* x1 = (const float4*)(X1 + (size_t)row * H_);
    bf16* o = XX + (size_t)p * (2 * H_);
    int i = threadIdx.x;  // 0..255, H/4 = 256
    float4 v = x[i];
    __align__(8) bf16 t[4];
    t[0] = __float2bfloat16(v.x); t[1] = __float2bfloat16(v.y);
    t[2] = __float2bfloat16(v.z); t[3] = __float2bfloat16(v.w);
    *(uint2*)(o + i * 4) = *(const uint2*)t;
    float4 w = x1[i];
    t[0] = __float2bfloat16(w.x); t[1] = __float2bfloat16(w.y);
    t[2] = __float2bfloat16(w.z); t[3] = __float2bfloat16(w.w);
    *(uint2*)(o + H_ + i * 4) = *(const uint2*)t;
}

// ---- transpose+convert W1,W2 -> WT12 and W3 -> WT3 ------------------------
// which = z>>4: 0 -> W1, 1 -> W2 (into WT12, row length 2H), 2 -> W3 (WT3).
__global__ __launch_bounds__(256) void transpose_k(const float* __restrict__ W1s,
                                                   const float* __restrict__ W2s,
                                                   const float* __restrict__ W3s,
                                                   bf16* __restrict__ WT12,
                                                   bf16* __restrict__ WT3) {
    __shared__ float tile[64][65];
    const int which = blockIdx.z >> 4;  // 0,1,2
    const int a = blockIdx.z & 15;
    const float* src = (which == 0) ? W1s : (which == 1) ? W2s : W3s;

    const int k0 = blockIdx.x * 64;
    const int n0 = blockIdx.y * 64;
    const float* s = src + (size_t)a * H_ * H_;
    const int tc = threadIdx.x & 15;   // float4 column
    const int tr = threadIdx.x >> 4;   // 0..15
#pragma unroll
    for (int r = 0; r < 64; r += 16) {
        float4 v = *(const float4*)(s + (size_t)(k0 + tr + r) * H_ + n0 + tc * 4);
        tile[tr + r][tc * 4 + 0] = v.x;
        tile[tr + r][tc * 4 + 1] = v.y;
        tile[tr + r][tc * 4 + 2] = v.z;
        tile[tr + r][tc * 4 + 3] = v.w;
    }
    __syncthreads();
    bf16* d;
    int ldK;
    if (which < 2) {
        d = WT12 + (size_t)a * H_ * (2 * H_) + which * H_;
        ldK = 2 * H_;
    } else {
        d = WT3 + (size_t)a * H_ * H_;
        ldK = H_;
    }
    const int wc = threadIdx.x & 7;   // k-chunk of 8
    const int wr = threadIdx.x >> 3;  // 0..31
#pragma unroll
    for (int r = 0; r < 64; r += 32) {
        const int n = wr + r;
        __align__(16) bf16 tmp[8];
#pragma unroll
        for (int j = 0; j < 8; j++) tmp[j] = __float2bfloat16(tile[wc * 8 + j][n]);
        *(uint4*)(d + (size_t)(n0 + n) * ldK + k0 + wc * 8) = *(const uint4*)tmp;
    }
}

// ---- bf16 GEMM: 256x256 tile, BK=64, 8 waves (2Mx4N), 64 KiB LDS ----------
// C[a][M][N] = A[a][M][K] @ Bt[a][N][K]^T + bias.
// SINGLE-buffered, 2 blocks/CU. Round 3/4 post-mortem: with 128 KB dbuf only
// 1 block/CU fits; all 8 waves then alternate (read-burst | MFMA-burst) in
// lockstep around the per-tile barrier -> LDS (~62us of work) and MFMA
// (~55us) SERIALIZE (MfmaUtil 42%, both pipes <50% busy). Round 4 proved
// more intra-block sync makes it worse. Fix = INTER-block overlap (m114):
// halve LDS to 64 KB so 2 blocks co-reside per CU; the neighbor block's
// MFMA bursts cover this block's DMA stall + read bursts, anti-phase,
// with zero added synchronization.
// Schedule (minimal race surface -- DMA never concurrent with reads):
//   for t: { STAGE(t); vmcnt(0); __syncthreads;   // tile landed+visible
//            reads(t) + 64 MFMA;                  // consumers pre-barrier
//            __syncthreads; }                     // reads retired -> reuse
// LDS XOR swizzle (16B chunk c ^= row&7): linear DMA dest + inverse-swizzled
// global source + swizzled read (both-sides rule). Bank conflicts = 0
// (measured round 3). XCD swizzle: bm fastest within an XCD (B panel
// L2-resident). No setprio (null-to-negative without phase role-split).
template <bool RELU>
__global__ __launch_bounds__(512) void gemm_bt(const bf16* __restrict__ Amat, size_t aStrideA,
                                               const bf16* __restrict__ Bt,
                                               const float* __restrict__ bias,
                                               bf16* __restrict__ C,
                                               int M, int N, int K) {
    __shared__ __align__(16) char smem[65536];  // A: 32KB | B: 32KB

    // XCD swizzle over 512 blocks (16a x 8bm x 4bn), 512 % 8 == 0.
    const int L = blockIdx.x;
    const int xcd = L & 7;
    const int g = L >> 3;
    const int bm = g & 7;
    const int bna = xcd + 8 * (g >> 3);
    const int bn = bna & 3;
    const int a = bna >> 2;

    const bf16* Ab = Amat + (size_t)a * aStrideA;
    const bf16* Bb = Bt + (size_t)a * (size_t)N * K;

    const int tid = threadIdx.x;
    const int lane = tid & 63;
    const int w = tid >> 6;           // 0..7
    const int lr = lane & 15;
    const int q = lane >> 4;          // 0..3
    const int wm = (w >> 2) * 128;    // wave row base within 256-tile
    const int wn = (w & 3) * 64;      // wave col base within 256-tile

    // LDS fragment-read byte offsets; row = 128B, 16B chunk index XOR-swizzled
    // by (row & 7).
    const int swz = lr & 7;
    const int aRd0 = (wm + lr) * 128 + ((q ^ swz) << 4);
    const int aRd1 = (wm + lr) * 128 + (((q + 4) ^ swz) << 4);
    const int bRd0 = (wn + lr) * 128 + ((q ^ swz) << 4);
    const int bRd1 = (wn + lr) * 128 + (((q + 4) ^ swz) << 4);

    // staging: wave w stages rows [w*32, w*32+32), 4 calls of 8 rows; lane l
    // -> row +(l>>3), LDS chunk l&7, global chunk (l&7)^(l>>3) (inverse
    // swizzle on the SOURCE side).
    const int sr = lane >> 3;
    const int sc = (lane & 7) ^ sr;
    const size_t k8 = (size_t)8 * K;
    const bf16* aSt = Ab + (size_t)(bm * 256 + w * 32 + sr) * K + sc * 8;
    const bf16* bSt = Bb + (size_t)(bn * 256 + w * 32 + sr) * K + sc * 8;
    char* AsL = smem + w * 4096;
    char* BsL = smem + 32768 + w * 4096;

    v4f acc[8][4];
#pragma unroll
    for (int i = 0; i < 8; i++)
#pragma unroll
        for (int j = 0; j < 4; j++) acc[i][j] = (v4f){0.f, 0.f, 0.f, 0.f};

    const int nk = K / 64;

#define STAGE(tt)                                        \
    {                                                    \
        const bf16* as_ = aSt + (size_t)(tt) * 64;       \
        const bf16* bs_ = bSt + (size_t)(tt) * 64;       \
        gl_lds16(as_,            AsL);                   \
        gl_lds16(as_ + k8,       AsL + 1024);            \
        gl_lds16(as_ + 2 * k8,   AsL + 2048);            \
        gl_lds16(as_ + 3 * k8,   AsL + 3072);            \
        gl_lds16(bs_,            BsL);                   \
        gl_lds16(bs_ + k8,       BsL + 1024);            \
        gl_lds16(bs_ + 2 * k8,   BsL + 2048);            \
        gl_lds16(bs_ + 3 * k8,   BsL + 3072);            \
    }

    for (int t = 0; t < nk; ++t) {
        STAGE(t);
        // own 8 DMA writes drained, then block-wide barrier: whole tile
        // visible; reads below cannot start earlier (acquire).
        asm volatile("s_waitcnt vmcnt(0)" ::: "memory");
        __syncthreads();

        const char* Ar = smem;
        const char* Br = smem + 32768;

        // ---- k-half 0: read + consume ----
        {
            v8bf a0[8], b0[4];
#pragma unroll
            for (int ni = 0; ni < 4; ni++) b0[ni] = *(const v8bf*)(Br + bRd0 + ni * 2048);
#pragma unroll
            for (int mi = 0; mi < 8; mi++) a0[mi] = *(const v8bf*)(Ar + aRd0 + mi * 2048);
#pragma unroll
            for (int mi = 0; mi < 8; mi++)
#pragma unroll
                for (int ni = 0; ni < 4; ni++)
                    acc[mi][ni] = __builtin_amdgcn_mfma_f32_16x16x32_bf16(a0[mi], b0[ni],
                                                                          acc[mi][ni], 0, 0, 0);
        }
        // ---- k-half 1: read + consume ----
        {
            v8bf a1[8], b1[4];
#pragma unroll
            for (int ni = 0; ni < 4; ni++) b1[ni] = *(const v8bf*)(Br + bRd1 + ni * 2048);
#pragma unroll
            for (int mi = 0; mi < 8; mi++) a1[mi] = *(const v8bf*)(Ar + aRd1 + mi * 2048);
#pragma unroll
            for (int mi = 0; mi < 8; mi++)
#pragma unroll
                for (int ni = 0; ni < 4; ni++)
                    acc[mi][ni] = __builtin_amdgcn_mfma_f32_16x16x32_bf16(a1[mi], b1[ni],
                                                                          acc[mi][ni], 0, 0, 0);
        }

        // all waves' reads of the buffer retired -> safe for next STAGE.
        __syncthreads();
    }
#undef STAGE

    // epilogue: C/D layout col=lane&15, row=(lane>>4)*4+reg
    bf16* Cb = C + (size_t)a * (size_t)M * N;
#pragma unroll
    for (int ni = 0; ni < 4; ni++) {
        const int col = bn * 256 + wn + ni * 16 + lr;
        const float bv = bias[(size_t)a * N + col];
#pragma unroll
        for (int mi = 0; mi < 8; mi++) {
            const int row0 = bm * 256 + wm + mi * 16 + q * 4;
#pragma unroll
            for (int rg = 0; rg < 4; rg++) {
                float v = acc[mi][ni][rg] + bv;
                if (RELU) v = v > 0.f ? v : 0.f;
                Cb[(size_t)(row0 + rg) * N + col] = __float2bfloat16(v);
            }
        }
    }
}

// ---- fused LayerNorm + [H]->[O] head: one wave per 4 rows of one a --------
__global__ __launch_bounds__(256) void ln_head_k(const bf16* __restrict__ Hb,  // [A][P][H]
                                                 const float* __restrict__ gamma,
                                                 const float* __restrict__ beta,
                                                 const float* __restrict__ W4,  // [A][H][O]
                                                 const float* __restrict__ b4,  // [A][O]
                                                 float* __restrict__ out) {     // [P][A*O]
    const int w = blockIdx.x * 4 + (threadIdx.x >> 6);  // wave id, 0..8191
    const int lane = threadIdx.x & 63;
    const int a = w >> 9;          // 512 waves per a
    const int p0 = (w & 511) * 4;  // 4 rows per wave
    const float* g = gamma + (size_t)a * H_;
    const float* be = beta + (size_t)a * H_;
    const float4* w4 = (const float4*)(W4 + (size_t)a * H_ * O_);

    float gv[16], bv[16];
    float4 wv[16];
#pragma unroll
    for (int half = 0; half < 2; half++) {
        const int kb = half * 512 + lane * 8;
        const float4 g4a = *(const float4*)(g + kb);
        const float4 g4b = *(const float4*)(g + kb + 4);
        const float4 b4a = *(const float4*)(be + kb);
        const float4 b4b = *(const float4*)(be + kb + 4);
        gv[half * 8 + 0] = g4a.x; gv[half * 8 + 1] = g4a.y;
        gv[half * 8 + 2] = g4a.z; gv[half * 8 + 3] = g4a.w;
        gv[half * 8 + 4] = g4b.x; gv[half * 8 + 5] = g4b.y;
        gv[half * 8 + 6] = g4b.z; gv[half * 8 + 7] = g4b.w;
        bv[half * 8 + 0] = b4a.x; bv[half * 8 + 1] = b4a.y;
        bv[half * 8 + 2] = b4a.z; bv[half * 8 + 3] = b4a.w;
        bv[half * 8 + 4] = b4b.x; bv[half * 8 + 5] = b4b.y;
        bv[half * 8 + 6] = b4b.z; bv[half * 8 + 7] = b4b.w;
#pragma unroll
        for (int j = 0; j < 8; j++) wv[half * 8 + j] = w4[kb + j];
    }
    const float bo = b4[a * O_ + (lane & 3)];

    for (int rr = 0; rr < 4; rr++) {
        const int p = p0 + rr;
        const bf16* hrow = Hb + ((size_t)a * P_ + p) * H_;
        v8bf h0 = *(const v8bf*)(hrow + lane * 8);
        v8bf h1 = *(const v8bf*)(hrow + 512 + lane * 8);
        float hv[16];
        float s = 0.f, ss = 0.f;
#pragma unroll
        for (int j = 0; j < 8; j++) {
            float v = (float)h0[j];
            hv[j] = v; s += v; ss += v * v;
        }
#pragma unroll
        for (int j = 0; j < 8; j++) {
            float v = (float)h1[j];
            hv[8 + j] = v; s += v; ss += v * v;
        }
#pragma unroll
        for (int off = 32; off; off >>= 1) {
            s += __shfl_xor(s, off);
            ss += __shfl_xor(ss, off);
        }
        const float mu = s * (1.f / H_);
        const float var = ss * (1.f / H_) - mu * mu;
        const float rstd = rsqrtf(var + EPS_);
        float a0 = 0.f, a1 = 0.f, a2 = 0.f, a3 = 0.f;
#pragma unroll
        for (int j = 0; j < 16; j++) {
            const float hn = (hv[j] - mu) * rstd * gv[j] + bv[j];
            a0 += hn * wv[j].x;
            a1 += hn * wv[j].y;
            a2 += hn * wv[j].z;
            a3 += hn * wv[j].w;
        }
#pragma unroll
        for (int off = 32; off; off >>= 1) {
            a0 += __shfl_xor(a0, off);
            a1 += __shfl_xor(a1, off);
            a2 += __shfl_xor(a2, off);
            a3 += __shfl_xor(a3, off);
        }
        if (lane < 4) {
            const float v = (lane == 0 ? a0 : lane == 1 ? a1 : lane == 2 ? a2 : a3) + bo;
            out[(size_t)p * (A_ * O_) + a * O_ + lane] = v;
        }
    }
}

extern "C" void kernel_launch(void* const* d_in, const int* in_sizes, int n_in,
                              void* d_out, int out_size, void* d_ws, size_t ws_size,
                              hipStream_t stream) {
    const float* X     = (const float*)d_in[0];
    const float* X1    = (const float*)d_in[1];
    const float* W1    = (const float*)d_in[2];
    const float* b1    = (const float*)d_in[3];
    const float* W2    = (const float*)d_in[4];
    const float* b2    = (const float*)d_in[5];
    const float* W3    = (const float*)d_in[6];
    const float* b3    = (const float*)d_in[7];
    const float* gamma = (const float*)d_in[8];
    const float* beta  = (const float*)d_in[9];
    const float* W4    = (const float*)d_in[10];
    const float* b4    = (const float*)d_in[11];
    const int* pos     = (const int*)d_in[12];
    float* out = (float*)d_out;

    char* ws = (char*)d_ws;
    bf16* XX   = (bf16*)(ws);                          // P*2H bf16   = 8 MB
    bf16* Z    = (bf16*)(ws + ((size_t)8 << 20));      // A*P*H bf16  = 64 MB
    bf16* WT3  = (bf16*)(ws + ((size_t)72 << 20));     // A*H*H bf16  = 32 MB
    bf16* WT12 = (bf16*)(ws + ((size_t)104 << 20));    // A*H*2H bf16 = 64 MB (dead after gemm1)
    float* b12 = (float*)(ws + ((size_t)168 << 20));   // A*H fp32    = 64 KB
    bf16* Hb   = WT12;                                 // alias: written by gemm2 after WT12 is dead

    gather_bias_k<<<P_ + 64, 256, 0, stream>>>(X, X1, pos, XX, b1, b2, b12);
    dim3 tgrid(H_ / 64, H_ / 64, 3 * A_);
    transpose_k<<<tgrid, 256, 0, stream>>>(W1, W2, W3, WT12, WT3);

    // gemm1: z = [X|X1] @ [W1;W2]^T + b12, K=2H  (A shared across a: stride 0)
    gemm_bt<false><<<512, 512, 0, stream>>>(XX, 0, WT12, b12, Z, P_, H_, 2 * H_);
    // gemm2: h = relu(z @ W3^T + b3), K=H
    gemm_bt<true><<<512, 512, 0, stream>>>(Z, (size_t)P_ * H_, WT3, b3, Hb, P_, H_, H_);

    ln_head_k<<<P_ * A_ / 16, 256, 0, stream>>>(Hb, gamma, beta, W4, b4, out);
}

// Round 6
// 484.213 us; speedup vs baseline: 1.0978x; 1.0978x over previous
//
#include <hip/hip_runtime.h>
#include <hip/hip_bf16.h>

using bf16 = __hip_bfloat16;
typedef __bf16 v8bf __attribute__((ext_vector_type(8)));
typedef float v4f __attribute__((ext_vector_type(4)));

#define H_ 1024
#define A_ 16
#define O_ 4
#define B_ 4096
#define P_ 2048
#define EPS_ 1e-5f

// async global->LDS, 16B per lane; lds pointer must be wave-uniform base.
__device__ __forceinline__ void gl_lds16(const void* g, void* l) {
    __builtin_amdgcn_global_load_lds(
        (const __attribute__((address_space(1))) void*)g,
        (__attribute__((address_space(3))) void*)l, 16, 0, 0);
}

// ---- gather selected rows of X,X1 -> XX (bf16); tail blocks do b12=b1+b2 --
__global__ __launch_bounds__(256) void gather_bias_k(const float* __restrict__ X,
                                                     const float* __restrict__ X1,
                                                     const int* __restrict__ pos,
                                                     bf16* __restrict__ XX,
                                                     const float* __restrict__ b1,
                                                     const float* __restrict__ b2,
                                                     float* __restrict__ b12) {
    if (blockIdx.x >= P_) {
        int i = (blockIdx.x - P_) * 256 + threadIdx.x;
        if (i < A_ * H_) b12[i] = b1[i] + b2[i];
        return;
    }
    int p = blockIdx.x;
    int row = pos[p];
    const float4* x  = (const float4*)(X  + (size_t)row * H_);
    const float4* x1 = (const float4*)(X1 + (size_t)row * H_);
    bf16* o = XX + (size_t)p * (2 * H_);
    int i = threadIdx.x;  // 0..255, H/4 = 256
    float4 v = x[i];
    __align__(8) bf16 t[4];
    t[0] = __float2bfloat16(v.x); t[1] = __float2bfloat16(v.y);
    t[2] = __float2bfloat16(v.z); t[3] = __float2bfloat16(v.w);
    *(uint2*)(o + i * 4) = *(const uint2*)t;
    float4 w = x1[i];
    t[0] = __float2bfloat16(w.x); t[1] = __float2bfloat16(w.y);
    t[2] = __float2bfloat16(w.z); t[3] = __float2bfloat16(w.w);
    *(uint2*)(o + H_ + i * 4) = *(const uint2*)t;
}

// ---- transpose+convert W1,W2 -> WT12 and W3 -> WT3 ------------------------
__global__ __launch_bounds__(256) void transpose_k(const float* __restrict__ W1s,
                                                   const float* __restrict__ W2s,
                                                   const float* __restrict__ W3s,
                                                   bf16* __restrict__ WT12,
                                                   bf16* __restrict__ WT3) {
    __shared__ float tile[64][65];
    const int which = blockIdx.z >> 4;  // 0,1,2
    const int a = blockIdx.z & 15;
    const float* src = (which == 0) ? W1s : (which == 1) ? W2s : W3s;

    const int k0 = blockIdx.x * 64;
    const int n0 = blockIdx.y * 64;
    const float* s = src + (size_t)a * H_ * H_;
    const int tc = threadIdx.x & 15;   // float4 column
    const int tr = threadIdx.x >> 4;   // 0..15
#pragma unroll
    for (int r = 0; r < 64; r += 16) {
        float4 v = *(const float4*)(s + (size_t)(k0 + tr + r) * H_ + n0 + tc * 4);
        tile[tr + r][tc * 4 + 0] = v.x;
        tile[tr + r][tc * 4 + 1] = v.y;
        tile[tr + r][tc * 4 + 2] = v.z;
        tile[tr + r][tc * 4 + 3] = v.w;
    }
    __syncthreads();
    bf16* d;
    int ldK;
    if (which < 2) {
        d = WT12 + (size_t)a * H_ * (2 * H_) + which * H_;
        ldK = 2 * H_;
    } else {
        d = WT3 + (size_t)a * H_ * H_;
        ldK = H_;
    }
    const int wc = threadIdx.x & 7;   // k-chunk of 8
    const int wr = threadIdx.x >> 3;  // 0..31
#pragma unroll
    for (int r = 0; r < 64; r += 32) {
        const int n = wr + r;
        __align__(16) bf16 tmp[8];
#pragma unroll
        for (int j = 0; j < 8; j++) tmp[j] = __float2bfloat16(tile[wc * 8 + j][n]);
        *(uint4*)(d + (size_t)(n0 + n) * ldK + k0 + wc * 8) = *(const uint4*)tmp;
    }
}

// ---- bf16 GEMM: 256x256 tile, BK=64, 8 waves (2Mx4N), 128 KiB LDS ---------
// C[a][M][N] = A[a][M][K] @ Bt[a][N][K]^T + bias.
// 4-phase counted-vmcnt pipeline (T3+T4+T2+T5, m201-template port).
// LDS: per matrix [dbuf d][khalf s] of 16 KB = 256 rows x 32 cols bf16
// (row = 64 B). A at smem, B at smem+64K. d = tile parity.
// Per K-tile t (d=t&1), 4 phases; phase p = { ds_read subtile (pre-barrier),
// stage ONE half-tile of t+1 into d^1, sched_barrier, s_barrier, setprio(1),
// 16 MFMA (consumers post-barrier), setprio(0), [vmcnt] , s_barrier }:
//   p0: read a[0-3](s0)+b(s0);  stage (t+1,A,s0);  mfma q0*k0
//   p1: read a[4-7](s0);        stage (t+1,B,s0);  mfma q1*k0; vmcnt(4)
//   p2: read a[0-3](s1)+b(s1);  stage (t+1,A,s1);  mfma q0*k1
//   p3: read a[4-7](s1);        stage (t+1,B,s1);  mfma q1*k1; vmcnt(4)
// vmcnt audit (2 stage-loads per phase per wave, exact):
//   p1-end vmcnt(4) leaves {t.p0,t.p1} in flight, drains {t-1.p2,t-1.p3}
//     = (t,A,s1),(t,B,s1) -- exactly what p2's reads need. Last tile: those
//     are the only outstanding 4 -> needs vmcnt(0) (uniform-branch peel).
//   p3-end vmcnt(4) drains {t.p0,t.p1} = (t+1,A,s0),(t+1,B,s0) -- exactly
//     what t+1.p0's reads need. Never 0 in steady loop.
// Race audit: reads cannot sink past their MFMA consumers; ALL stages in
// tile t write dbuf d^1 while ALL reads hit d -> disjoint (the R1 sink-race
// is structurally impossible). Each vmcnt precedes a barrier, so one wave's
// drain + barrier => every wave's stages for that half are landed before
// any read of it is issued. A region is re-staged >=2 barriers after its
// last reader retired (WAR-safe).
// Swizzle: LDS[row][chunk c] (c = 16B chunk of 4) holds global chunk
// c ^ ((row>>1)&3); read addr uses the same XOR; staging source pre-applies
// it (both-sides rule). Wave's 16-lane column read -> 2-way conflict (free).
template <bool RELU>
__global__ __launch_bounds__(512) void gemm_bt(const bf16* __restrict__ Amat, size_t aStrideA,
                                               const bf16* __restrict__ Bt,
                                               const float* __restrict__ bias,
                                               bf16* __restrict__ C,
                                               int M, int N, int K) {
    __shared__ __align__(16) char smem[131072];

    // XCD swizzle over 512 blocks (16a x 8bm x 4bn), 512 % 8 == 0.
    const int L = blockIdx.x;
    const int xcd = L & 7;
    const int g = L >> 3;
    const int bm = g & 7;
    const int bna = xcd + 8 * (g >> 3);
    const int bn = bna & 3;
    const int a = bna >> 2;

    const bf16* Ab = Amat + (size_t)a * aStrideA;
    const bf16* Bb = Bt + (size_t)a * (size_t)N * K;

    const int tid = threadIdx.x;
    const int lane = tid & 63;
    const int w = tid >> 6;           // 0..7
    const int lr = lane & 15;
    const int q = lane >> 4;          // 0..3
    const int wm = (w >> 2) * 128;    // wave row base within 256-tile
    const int wn = (w & 3) * 64;      // wave col base within 256-tile

    // fragment-read byte offsets within a 16 KB half (row=64B, chunk XOR'd)
    const int swz = (lr >> 1) & 3;
    const int aBase = (wm + lr) * 64 + ((q ^ swz) << 4);
    const int bBase = (wn + lr) * 64 + ((q ^ swz) << 4);

    // staging: wave w stages rows w*32..w*32+31 of a half (2 calls x 16 rows).
    // lane l -> row +(l>>2), LDS chunk l&3; global chunk (l&3)^((l>>3)&3)
    // (inverse swizzle on the SOURCE side; (row>>1)&3 == (l>>3)&3 here).
    const int grow = lane >> 2;
    const int gch = ((lane & 3) ^ ((lane >> 3) & 3)) * 8;
    const bf16* aG = Ab + (size_t)(bm * 256 + w * 32 + grow) * K + gch;
    const bf16* bG = Bb + (size_t)(bn * 256 + w * 32 + grow) * K + gch;
    const size_t k16 = (size_t)16 * K;
    char* AsM = smem;            // + d*32768 + s*16384 + w*2048 (+1024 call 1)
    char* BsM = smem + 65536;

    v4f acc[8][4];
#pragma unroll
    for (int i = 0; i < 8; i++)
#pragma unroll
        for (int j = 0; j < 4; j++) acc[i][j] = (v4f){0.f, 0.f, 0.f, 0.f};

    const int nk = K / 64;

#define STG(gp, base, dd, ss, tt)                                              \
    {                                                                          \
        gl_lds16((gp) + (size_t)(tt) * 64 + (ss) * 32,                         \
                 (base) + (dd) * 32768 + (ss) * 16384 + w * 2048);             \
        gl_lds16((gp) + (size_t)(tt) * 64 + (ss) * 32 + k16,                   \
                 (base) + (dd) * 32768 + (ss) * 16384 + w * 2048 + 1024);      \
    }

    // prologue: all 4 halves of tile 0 into dbuf 0; full drain (once).
    STG(aG, AsM, 0, 0, 0)
    STG(bG, BsM, 0, 0, 0)
    STG(aG, AsM, 0, 1, 0)
    STG(bG, BsM, 0, 1, 0)
    asm volatile("s_waitcnt vmcnt(0)" ::: "memory");
    __syncthreads();

    for (int t = 0; t < nk; ++t) {
        const int d = t & 1, nd = d ^ 1;
        const char* Ad = smem + d * 32768;
        const char* Bd = smem + 65536 + d * 32768;
        const bool pf = (t + 1 < nk);

        v8bf av[4], bv[4];

        // ---------------- p0 ----------------
#pragma unroll
        for (int ni = 0; ni < 4; ni++) bv[ni] = *(const v8bf*)(Bd + bBase + ni * 1024);
#pragma unroll
        for (int mi = 0; mi < 4; mi++) av[mi] = *(const v8bf*)(Ad + aBase + mi * 1024);
        if (pf) STG(aG, AsM, nd, 0, t + 1)
        __builtin_amdgcn_sched_barrier(0);
        __builtin_amdgcn_s_barrier();
        __builtin_amdgcn_s_setprio(1);
#pragma unroll
        for (int mi = 0; mi < 4; mi++)
#pragma unroll
            for (int ni = 0; ni < 4; ni++)
                acc[mi][ni] = __builtin_amdgcn_mfma_f32_16x16x32_bf16(av[mi], bv[ni],
                                                                      acc[mi][ni], 0, 0, 0);
        __builtin_amdgcn_s_setprio(0);
        __builtin_amdgcn_s_barrier();

        // ---------------- p1 ----------------
#pragma unroll
        for (int mi = 0; mi < 4; mi++) av[mi] = *(const v8bf*)(Ad + aBase + (mi + 4) * 1024);
        if (pf) STG(bG, BsM, nd, 0, t + 1)
        __builtin_amdgcn_sched_barrier(0);
        __builtin_amdgcn_s_barrier();
        __builtin_amdgcn_s_setprio(1);
#pragma unroll
        for (int mi = 0; mi < 4; mi++)
#pragma unroll
            for (int ni = 0; ni < 4; ni++)
                acc[mi + 4][ni] = __builtin_amdgcn_mfma_f32_16x16x32_bf16(av[mi], bv[ni],
                                                                          acc[mi + 4][ni], 0, 0, 0);
        __builtin_amdgcn_s_setprio(0);
        if (pf) {
            asm volatile("s_waitcnt vmcnt(4)" ::: "memory");  // drains (t,A,s1),(t,B,s1)
        } else {
            asm volatile("s_waitcnt vmcnt(0)" ::: "memory");  // last tile: they're newest
        }
        __builtin_amdgcn_s_barrier();

        // ---------------- p2 (k-half s1) ----------------
#pragma unroll
        for (int ni = 0; ni < 4; ni++) bv[ni] = *(const v8bf*)(Bd + 16384 + bBase + ni * 1024);
#pragma unroll
        for (int mi = 0; mi < 4; mi++) av[mi] = *(const v8bf*)(Ad + 16384 + aBase + mi * 1024);
        if (pf) STG(aG, AsM, nd, 1, t + 1)
        __builtin_amdgcn_sched_barrier(0);
        __builtin_amdgcn_s_barrier();
        __builtin_amdgcn_s_setprio(1);
#pragma unroll
        for (int mi = 0; mi < 4; mi++)
#pragma unroll
            for (int ni = 0; ni < 4; ni++)
                acc[mi][ni] = __builtin_amdgcn_mfma_f32_16x16x32_bf16(av[mi], bv[ni],
                                                                      acc[mi][ni], 0, 0, 0);
        __builtin_amdgcn_s_setprio(0);
        __builtin_amdgcn_s_barrier();

        // ---------------- p3 ----------------
#pragma unroll
        for (int mi = 0; mi < 4; mi++) av[mi] = *(const v8bf*)(Ad + 16384 + aBase + (mi + 4) * 1024);
        if (pf) STG(bG, BsM, nd, 1, t + 1)
        __builtin_amdgcn_sched_barrier(0);
        __builtin_amdgcn_s_barrier();
        __builtin_amdgcn_s_setprio(1);
#pragma unroll
        for (int mi = 0; mi < 4; mi++)
#pragma unroll
            for (int ni = 0; ni < 4; ni++)
                acc[mi + 4][ni] = __builtin_amdgcn_mfma_f32_16x16x32_bf16(av[mi], bv[ni],
                                                                          acc[mi + 4][ni], 0, 0, 0);
        __builtin_amdgcn_s_setprio(0);
        asm volatile("s_waitcnt vmcnt(4)" ::: "memory");  // drains (t+1,A,s0),(t+1,B,s0); last tile: no-op
        __builtin_amdgcn_s_barrier();
    }
#undef STG

    // epilogue: C/D layout col=lane&15, row=(lane>>4)*4+reg
    bf16* Cb = C + (size_t)a * (size_t)M * N;
#pragma unroll
    for (int ni = 0; ni < 4; ni++) {
        const int col = bn * 256 + wn + ni * 16 + lr;
        const float bv2 = bias[(size_t)a * N + col];
#pragma unroll
        for (int mi = 0; mi < 8; mi++) {
            const int row0 = bm * 256 + wm + mi * 16 + q * 4;
#pragma unroll
            for (int rg = 0; rg < 4; rg++) {
                float v = acc[mi][ni][rg] + bv2;
                if (RELU) v = v > 0.f ? v : 0.f;
                Cb[(size_t)(row0 + rg) * N + col] = __float2bfloat16(v);
            }
        }
    }
}

// ---- fused LayerNorm + [H]->[O] head: one wave per 4 rows of one a --------
__global__ __launch_bounds__(256) void ln_head_k(const bf16* __restrict__ Hb,  // [A][P][H]
                                                 const float* __restrict__ gamma,
                                                 const float* __restrict__ beta,
                                                 const float* __restrict__ W4,  // [A][H][O]
                                                 const float* __restrict__ b4,  // [A][O]
                                                 float* __restrict__ out) {     // [P][A*O]
    const int w = blockIdx.x * 4 + (threadIdx.x >> 6);  // wave id, 0..8191
    const int lane = threadIdx.x & 63;
    const int a = w >> 9;          // 512 waves per a
    const int p0 = (w & 511) * 4;  // 4 rows per wave
    const float* g = gamma + (size_t)a * H_;
    const float* be = beta + (size_t)a * H_;
    const float4* w4 = (const float4*)(W4 + (size_t)a * H_ * O_);

    float gv[16], bv[16];
    float4 wv[16];
#pragma unroll
    for (int half = 0; half < 2; half++) {
        const int kb = half * 512 + lane * 8;
        const float4 g4a = *(const float4*)(g + kb);
        const float4 g4b = *(const float4*)(g + kb + 4);
        const float4 b4a = *(const float4*)(be + kb);
        const float4 b4b = *(const float4*)(be + kb + 4);
        gv[half * 8 + 0] = g4a.x; gv[half * 8 + 1] = g4a.y;
        gv[half * 8 + 2] = g4a.z; gv[half * 8 + 3] = g4a.w;
        gv[half * 8 + 4] = g4b.x; gv[half * 8 + 5] = g4b.y;
        gv[half * 8 + 6] = g4b.z; gv[half * 8 + 7] = g4b.w;
        bv[half * 8 + 0] = b4a.x; bv[half * 8 + 1] = b4a.y;
        bv[half * 8 + 2] = b4a.z; bv[half * 8 + 3] = b4a.w;
        bv[half * 8 + 4] = b4b.x; bv[half * 8 + 5] = b4b.y;
        bv[half * 8 + 6] = b4b.z; bv[half * 8 + 7] = b4b.w;
#pragma unroll
        for (int j = 0; j < 8; j++) wv[half * 8 + j] = w4[kb + j];
    }
    const float bo = b4[a * O_ + (lane & 3)];

    for (int rr = 0; rr < 4; rr++) {
        const int p = p0 + rr;
        const bf16* hrow = Hb + ((size_t)a * P_ + p) * H_;
        v8bf h0 = *(const v8bf*)(hrow + lane * 8);
        v8bf h1 = *(const v8bf*)(hrow + 512 + lane * 8);
        float hv[16];
        float s = 0.f, ss = 0.f;
#pragma unroll
        for (int j = 0; j < 8; j++) {
            float v = (float)h0[j];
            hv[j] = v; s += v; ss += v * v;
        }
#pragma unroll
        for (int j = 0; j < 8; j++) {
            float v = (float)h1[j];
            hv[8 + j] = v; s += v; ss += v * v;
        }
#pragma unroll
        for (int off = 32; off; off >>= 1) {
            s += __shfl_xor(s, off);
            ss += __shfl_xor(ss, off);
        }
        const float mu = s * (1.f / H_);
        const float var = ss * (1.f / H_) - mu * mu;
        const float rstd = rsqrtf(var + EPS_);
        float a0 = 0.f, a1 = 0.f, a2 = 0.f, a3 = 0.f;
#pragma unroll
        for (int j = 0; j < 16; j++) {
            const float hn = (hv[j] - mu) * rstd * gv[j] + bv[j];
            a0 += hn * wv[j].x;
            a1 += hn * wv[j].y;
            a2 += hn * wv[j].z;
            a3 += hn * wv[j].w;
        }
#pragma unroll
        for (int off = 32; off; off >>= 1) {
            a0 += __shfl_xor(a0, off);
            a1 += __shfl_xor(a1, off);
            a2 += __shfl_xor(a2, off);
            a3 += __shfl_xor(a3, off);
        }
        if (lane < 4) {
            const float v = (lane == 0 ? a0 : lane == 1 ? a1 : lane == 2 ? a2 : a3) + bo;
            out[(size_t)p * (A_ * O_) + a * O_ + lane] = v;
        }
    }
}

extern "C" void kernel_launch(void* const* d_in, const int* in_sizes, int n_in,
                              void* d_out, int out_size, void* d_ws, size_t ws_size,
                              hipStream_t stream) {
    const float* X     = (const float*)d_in[0];
    const float* X1    = (const float*)d_in[1];
    const float* W1    = (const float*)d_in[2];
    const float* b1    = (const float*)d_in[3];
    const float* W2    = (const float*)d_in[4];
    const float* b2    = (const float*)d_in[5];
    const float* W3    = (const float*)d_in[6];
    const float* b3    = (const float*)d_in[7];
    const float* gamma = (const float*)d_in[8];
    const float* beta  = (const float*)d_in[9];
    const float* W4    = (const float*)d_in[10];
    const float* b4    = (const float*)d_in[11];
    const int* pos     = (const int*)d_in[12];
    float* out = (float*)d_out;

    char* ws = (char*)d_ws;
    bf16* XX   = (bf16*)(ws);                          // P*2H bf16   = 8 MB
    bf16* Z    = (bf16*)(ws + ((size_t)8 << 20));      // A*P*H bf16  = 64 MB
    bf16* WT3  = (bf16*)(ws + ((size_t)72 << 20));     // A*H*H bf16  = 32 MB
    bf16* WT12 = (bf16*)(ws + ((size_t)104 << 20));    // A*H*2H bf16 = 64 MB (dead after gemm1)
    float* b12 = (float*)(ws + ((size_t)168 << 20));   // A*H fp32    = 64 KB
    bf16* Hb   = WT12;                                 // alias: written by gemm2 after WT12 is dead

    gather_bias_k<<<P_ + 64, 256, 0, stream>>>(X, X1, pos, XX, b1, b2, b12);
    dim3 tgrid(H_ / 64, H_ / 64, 3 * A_);
    transpose_k<<<tgrid, 256, 0, stream>>>(W1, W2, W3, WT12, WT3);

    // gemm1: z = [X|X1] @ [W1;W2]^T + b12, K=2H  (A shared across a: stride 0)
    gemm_bt<false><<<512, 512, 0, stream>>>(XX, 0, WT12, b12, Z, P_, H_, 2 * H_);
    // gemm2: h = relu(z @ W3^T + b3), K=H
    gemm_bt<true><<<512, 512, 0, stream>>>(Z, (size_t)P_ * H_, WT3, b3, Hb, P_, H_, H_);

    ln_head_k<<<P_ * A_ / 16, 256, 0, stream>>>(Hb, gamma, beta, W4, b4, out);
}

// Round 7
// 462.099 us; speedup vs baseline: 1.1504x; 1.0479x over previous
//
#include <hip/hip_runtime.h>
#include <hip/hip_bf16.h>

using bf16 = __hip_bfloat16;
typedef __bf16 v8bf __attribute__((ext_vector_type(8)));
typedef float v16f __attribute__((ext_vector_type(16)));

#define H_ 1024
#define A_ 16
#define O_ 4
#define B_ 4096
#define P_ 2048
#define EPS_ 1e-5f

// async global->LDS, 16B per lane; lds pointer must be wave-uniform base.
__device__ __forceinline__ void gl_lds16(const void* g, void* l) {
    __builtin_amdgcn_global_load_lds(
        (const __attribute__((address_space(1))) void*)g,
        (__attribute__((address_space(3))) void*)l, 16, 0, 0);
}

// ---- gather selected rows of X,X1 -> XX (bf16); tail blocks do b12=b1+b2 --
__global__ __launch_bounds__(256) void gather_bias_k(const float* __restrict__ X,
                                                     const float* __restrict__ X1,
                                                     const int* __restrict__ pos,
                                                     bf16* __restrict__ XX,
                                                     const float* __restrict__ b1,
                                                     const float* __restrict__ b2,
                                                     float* __restrict__ b12) {
    if (blockIdx.x >= P_) {
        int i = (blockIdx.x - P_) * 256 + threadIdx.x;
        if (i < A_ * H_) b12[i] = b1[i] + b2[i];
        return;
    }
    int p = blockIdx.x;
    int row = pos[p];
    const float4* x  = (const float4*)(X  + (size_t)row * H_);
    const float4* x1 = (const float4*)(X1 + (size_t)row * H_);
    bf16* o = XX + (size_t)p * (2 * H_);
    int i = threadIdx.x;  // 0..255, H/4 = 256
    float4 v = x[i];
    __align__(8) bf16 t[4];
    t[0] = __float2bfloat16(v.x); t[1] = __float2bfloat16(v.y);
    t[2] = __float2bfloat16(v.z); t[3] = __float2bfloat16(v.w);
    *(uint2*)(o + i * 4) = *(const uint2*)t;
    float4 w = x1[i];
    t[0] = __float2bfloat16(w.x); t[1] = __float2bfloat16(w.y);
    t[2] = __float2bfloat16(w.z); t[3] = __float2bfloat16(w.w);
    *(uint2*)(o + H_ + i * 4) = *(const uint2*)t;
}

// ---- transpose+convert W1,W2 -> WT12 and W3 -> WT3 ------------------------
__global__ __launch_bounds__(256) void transpose_k(const float* __restrict__ W1s,
                                                   const float* __restrict__ W2s,
                                                   const float* __restrict__ W3s,
                                                   bf16* __restrict__ WT12,
                                                   bf16* __restrict__ WT3) {
    __shared__ float tile[64][65];
    const int which = blockIdx.z >> 4;  // 0,1,2
    const int a = blockIdx.z & 15;
    const float* src = (which == 0) ? W1s : (which == 1) ? W2s : W3s;

    const int k0 = blockIdx.x * 64;
    const int n0 = blockIdx.y * 64;
    const float* s = src + (size_t)a * H_ * H_;
    const int tc = threadIdx.x & 15;   // float4 column
    const int tr = threadIdx.x >> 4;   // 0..15
#pragma unroll
    for (int r = 0; r < 64; r += 16) {
        float4 v = *(const float4*)(s + (size_t)(k0 + tr + r) * H_ + n0 + tc * 4);
        tile[tr + r][tc * 4 + 0] = v.x;
        tile[tr + r][tc * 4 + 1] = v.y;
        tile[tr + r][tc * 4 + 2] = v.z;
        tile[tr + r][tc * 4 + 3] = v.w;
    }
    __syncthreads();
    bf16* d;
    int ldK;
    if (which < 2) {
        d = WT12 + (size_t)a * H_ * (2 * H_) + which * H_;
        ldK = 2 * H_;
    } else {
        d = WT3 + (size_t)a * H_ * H_;
        ldK = H_;
    }
    const int wc = threadIdx.x & 7;   // k-chunk of 8
    const int wr = threadIdx.x >> 3;  // 0..31
#pragma unroll
    for (int r = 0; r < 64; r += 32) {
        const int n = wr + r;
        __align__(16) bf16 tmp[8];
#pragma unroll
        for (int j = 0; j < 8; j++) tmp[j] = __float2bfloat16(tile[wc * 8 + j][n]);
        *(uint4*)(d + (size_t)(n0 + n) * ldK + k0 + wc * 8) = *(const uint4*)tmp;
    }
}

// ---- bf16 GEMM: 256x256 tile, BK=64, 8 waves (2Mx4N), 128 KiB LDS ---------
// C[a][M][N] = A[a][M][K] @ Bt[a][N][K]^T + bias.
// Schedule = round-3 PROVEN shape (best of 4 schedule variants tested;
// R4 phases -12%, R5 single-buf -28%, R6 counted-vmcnt 4-phase null):
//   for t: { vmcnt(0); barrier; STAGE(t+1, other buf); reads(t)+MFMAs(t) }
// This round's single change: 16x16x32 -> 32x32x16 MFMA. Rationale: per-tile
// critical path measured additive (LDS ~2300 cyc + MFMA ~2480 cyc); 32x32
// runs at 2495 TF vs 2176 (m119, +15%) and halves MFMA instruction count
// (32 vs 64 per tile per wave) at IDENTICAL ds_read count (24 x b128) and
// identical LDS layout/swizzle -> cuts the MFMA-pipe term ~17%.
// Fragment mapping (32x32x16): A lane l -> row l&31, k = (l>>5)*8+j;
// B symmetric (col l&31); C/D col=lane&31, row=(r&3)+8*(r>>2)+4*(lane>>5)
// [m74/m101-verified]. LDS rows 128B, 16B-chunk XOR swizzle by (row&7):
// read chunk for k-step s = (2s + (l>>5)) ^ (row&7); staging stores global
// chunk c^(row&7) at LDS chunk c (both-sides rule; 0 conflicts measured R3).
template <bool RELU>
__global__ __launch_bounds__(512) void gemm_bt(const bf16* __restrict__ Amat, size_t aStrideA,
                                               const bf16* __restrict__ Bt,
                                               const float* __restrict__ bias,
                                               bf16* __restrict__ C,
                                               int M, int N, int K) {
    __shared__ __align__(16) char smem[131072];  // A: 2x32KB, B: 2x32KB

    // XCD swizzle over 512 blocks (16a x 8bm x 4bn), 512 % 8 == 0.
    const int L = blockIdx.x;
    const int xcd = L & 7;
    const int g = L >> 3;
    const int bm = g & 7;
    const int bna = xcd + 8 * (g >> 3);
    const int bn = bna & 3;
    const int a = bna >> 2;

    const bf16* Ab = Amat + (size_t)a * aStrideA;
    const bf16* Bb = Bt + (size_t)a * (size_t)N * K;

    const int tid = threadIdx.x;
    const int lane = tid & 63;
    const int w = tid >> 6;           // 0..7
    const int lc = lane & 31;         // A-row / B-col within a 32-block
    const int hi = lane >> 5;         // k-octet selector
    const int wm = (w >> 2) * 128;    // wave row base within 256-tile
    const int wn = (w & 3) * 64;      // wave col base within 256-tile

    // staging: wave w stages rows [w*32, w*32+32), 4 calls of 8 rows; lane l
    // -> row +(l>>3), LDS chunk l&7, global chunk (l&7)^(l>>3) (inverse
    // swizzle on the SOURCE side; row&7 == l>>3 here).
    const int sr = lane >> 3;
    const int sc = (lane & 7) ^ sr;
    const size_t k8 = (size_t)8 * K;
    const bf16* aSt = Ab + (size_t)(bm * 256 + w * 32 + sr) * K + sc * 8;
    const bf16* bSt = Bb + (size_t)(bn * 256 + w * 32 + sr) * K + sc * 8;
    char* AsL = smem + w * 4096;
    char* BsL = smem + 65536 + w * 4096;

    v16f acc[4][2];
#pragma unroll
    for (int i = 0; i < 4; i++)
#pragma unroll
        for (int j = 0; j < 2; j++)
#pragma unroll
            for (int r = 0; r < 16; r++) acc[i][j][r] = 0.f;

    const int nk = K / 64;

#define STAGE(tt, bo)                                    \
    {                                                    \
        const bf16* as_ = aSt + (size_t)(tt) * 64;       \
        const bf16* bs_ = bSt + (size_t)(tt) * 64;       \
        gl_lds16(as_,            AsL + (bo));            \
        gl_lds16(as_ + k8,       AsL + (bo) + 1024);     \
        gl_lds16(as_ + 2 * k8,   AsL + (bo) + 2048);     \
        gl_lds16(as_ + 3 * k8,   AsL + (bo) + 3072);     \
        gl_lds16(bs_,            BsL + (bo));            \
        gl_lds16(bs_ + k8,       BsL + (bo) + 1024);     \
        gl_lds16(bs_ + 2 * k8,   BsL + (bo) + 2048);     \
        gl_lds16(bs_ + 3 * k8,   BsL + (bo) + 3072);     \
    }

    // prologue: tile 0 into buf0
    STAGE(0, 0);

    for (int t = 0; t < nk; ++t) {
        const int bo = (t & 1) << 15;
        // per-wave drain of own stages for tile t (issued one full K-tile
        // ago -> latency covered), then block-wide barrier: tile t visible,
        // all reads of tile t-1 retired -> its buffer is DMA-safe.
        asm volatile("s_waitcnt vmcnt(0)" ::: "memory");
        __syncthreads();
        if (t + 1 < nk) STAGE(t + 1, bo ^ 32768);

        const char* Ar = smem + bo;
        const char* Br = smem + 65536 + bo;

        // 4 k-steps of 16; per step: 6 ds_read_b128 + 8 MFMA. All consumers
        // precede the loop-top barrier (no consumer-less fence crossing).
#pragma unroll
        for (int s = 0; s < 4; ++s) {
            const int ch = (((2 * s + hi) ^ (lc & 7)) << 4);
            v8bf bvf[2], av[4];
#pragma unroll
            for (int nb = 0; nb < 2; nb++)
                bvf[nb] = *(const v8bf*)(Br + (wn + nb * 32 + lc) * 128 + ch);
#pragma unroll
            for (int mb = 0; mb < 4; mb++)
                av[mb] = *(const v8bf*)(Ar + (wm + mb * 32 + lc) * 128 + ch);
#pragma unroll
            for (int mb = 0; mb < 4; mb++)
#pragma unroll
                for (int nb = 0; nb < 2; nb++)
                    acc[mb][nb] = __builtin_amdgcn_mfma_f32_32x32x16_bf16(
                        av[mb], bvf[nb], acc[mb][nb], 0, 0, 0);
        }
    }
#undef STAGE

    // epilogue: C/D layout col=lane&31, row=(r&3)+8*(r>>2)+4*(lane>>5)
    bf16* Cb = C + (size_t)a * (size_t)M * N;
#pragma unroll
    for (int nb = 0; nb < 2; nb++) {
        const int col = bn * 256 + wn + nb * 32 + lc;
        const float bv2 = bias[(size_t)a * N + col];
#pragma unroll
        for (int mb = 0; mb < 4; mb++) {
            const int row0 = bm * 256 + wm + mb * 32 + hi * 4;
#pragma unroll
            for (int r = 0; r < 16; r++) {
                const int row = row0 + (r & 3) + 8 * (r >> 2);
                float v = acc[mb][nb][r] + bv2;
                if (RELU) v = v > 0.f ? v : 0.f;
                Cb[(size_t)row * N + col] = __float2bfloat16(v);
            }
        }
    }
}

// ---- fused LayerNorm + [H]->[O] head: one wave per 4 rows of one a --------
__global__ __launch_bounds__(256) void ln_head_k(const bf16* __restrict__ Hb,  // [A][P][H]
                                                 const float* __restrict__ gamma,
                                                 const float* __restrict__ beta,
                                                 const float* __restrict__ W4,  // [A][H][O]
                                                 const float* __restrict__ b4,  // [A][O]
                                                 float* __restrict__ out) {     // [P][A*O]
    const int w = blockIdx.x * 4 + (threadIdx.x >> 6);  // wave id, 0..8191
    const int lane = threadIdx.x & 63;
    const int a = w >> 9;          // 512 waves per a
    const int p0 = (w & 511) * 4;  // 4 rows per wave
    const float* g = gamma + (size_t)a * H_;
    const float* be = beta + (size_t)a * H_;
    const float4* w4 = (const float4*)(W4 + (size_t)a * H_ * O_);

    float gv[16], bv[16];
    float4 wv[16];
#pragma unroll
    for (int half = 0; half < 2; half++) {
        const int kb = half * 512 + lane * 8;
        const float4 g4a = *(const float4*)(g + kb);
        const float4 g4b = *(const float4*)(g + kb + 4);
        const float4 b4a = *(const float4*)(be + kb);
        const float4 b4b = *(const float4*)(be + kb + 4);
        gv[half * 8 + 0] = g4a.x; gv[half * 8 + 1] = g4a.y;
        gv[half * 8 + 2] = g4a.z; gv[half * 8 + 3] = g4a.w;
        gv[half * 8 + 4] = g4b.x; gv[half * 8 + 5] = g4b.y;
        gv[half * 8 + 6] = g4b.z; gv[half * 8 + 7] = g4b.w;
        bv[half * 8 + 0] = b4a.x; bv[half * 8 + 1] = b4a.y;
        bv[half * 8 + 2] = b4a.z; bv[half * 8 + 3] = b4a.w;
        bv[half * 8 + 4] = b4b.x; bv[half * 8 + 5] = b4b.y;
        bv[half * 8 + 6] = b4b.z; bv[half * 8 + 7] = b4b.w;
#pragma unroll
        for (int j = 0; j < 8; j++) wv[half * 8 + j] = w4[kb + j];
    }
    const float bo = b4[a * O_ + (lane & 3)];

    for (int rr = 0; rr < 4; rr++) {
        const int p = p0 + rr;
        const bf16* hrow = Hb + ((size_t)a * P_ + p) * H_;
        v8bf h0 = *(const v8bf*)(hrow + lane * 8);
        v8bf h1 = *(const v8bf*)(hrow + 512 + lane * 8);
        float hv[16];
        float s = 0.f, ss = 0.f;
#pragma unroll
        for (int j = 0; j < 8; j++) {
            float v = (float)h0[j];
            hv[j] = v; s += v; ss += v * v;
        }
#pragma unroll
        for (int j = 0; j < 8; j++) {
            float v = (float)h1[j];
            hv[8 + j] = v; s += v; ss += v * v;
        }
#pragma unroll
        for (int off = 32; off; off >>= 1) {
            s += __shfl_xor(s, off);
            ss += __shfl_xor(ss, off);
        }
        const float mu = s * (1.f / H_);
        const float var = ss * (1.f / H_) - mu * mu;
        const float rstd = rsqrtf(var + EPS_);
        float a0 = 0.f, a1 = 0.f, a2 = 0.f, a3 = 0.f;
#pragma unroll
        for (int j = 0; j < 16; j++) {
            const float hn = (hv[j] - mu) * rstd * gv[j] + bv[j];
            a0 += hn * wv[j].x;
            a1 += hn * wv[j].y;
            a2 += hn * wv[j].z;
            a3 += hn * wv[j].w;
        }
#pragma unroll
        for (int off = 32; off; off >>= 1) {
            a0 += __shfl_xor(a0, off);
            a1 += __shfl_xor(a1, off);
            a2 += __shfl_xor(a2, off);
            a3 += __shfl_xor(a3, off);
        }
        if (lane < 4) {
            const float v = (lane == 0 ? a0 : lane == 1 ? a1 : lane == 2 ? a2 : a3) + bo;
            out[(size_t)p * (A_ * O_) + a * O_ + lane] = v;
        }
    }
}

extern "C" void kernel_launch(void* const* d_in, const int* in_sizes, int n_in,
                              void* d_out, int out_size, void* d_ws, size_t ws_size,
                              hipStream_t stream) {
    const float* X     = (const float*)d_in[0];
    const float* X1    = (const float*)d_in[1];
    const float* W1    = (const float*)d_in[2];
    const float* b1    = (const float*)d_in[3];
    const float* W2    = (const float*)d_in[4];
    const float* b2    = (const float*)d_in[5];
    const float* W3    = (const float*)d_in[6];
    const float* b3    = (const float*)d_in[7];
    const float* gamma = (const float*)d_in[8];
    const float* beta  = (const float*)d_in[9];
    const float* W4    = (const float*)d_in[10];
    const float* b4    = (const float*)d_in[11];
    const int* pos     = (const int*)d_in[12];
    float* out = (float*)d_out;

    char* ws = (char*)d_ws;
    bf16* XX   = (bf16*)(ws);                          // P*2H bf16   = 8 MB
    bf16* Z    = (bf16*)(ws + ((size_t)8 << 20));      // A*P*H bf16  = 64 MB
    bf16* WT3  = (bf16*)(ws + ((size_t)72 << 20));     // A*H*H bf16  = 32 MB
    bf16* WT12 = (bf16*)(ws + ((size_t)104 << 20));    // A*H*2H bf16 = 64 MB (dead after gemm1)
    float* b12 = (float*)(ws + ((size_t)168 << 20));   // A*H fp32    = 64 KB
    bf16* Hb   = WT12;                                 // alias: written by gemm2 after WT12 is dead

    gather_bias_k<<<P_ + 64, 256, 0, stream>>>(X, X1, pos, XX, b1, b2, b12);
    dim3 tgrid(H_ / 64, H_ / 64, 3 * A_);
    transpose_k<<<tgrid, 256, 0, stream>>>(W1, W2, W3, WT12, WT3);

    // gemm1: z = [X|X1] @ [W1;W2]^T + b12, K=2H  (A shared across a: stride 0)
    gemm_bt<false><<<512, 512, 0, stream>>>(XX, 0, WT12, b12, Z, P_, H_, 2 * H_);
    // gemm2: h = relu(z @ W3^T + b3), K=H
    gemm_bt<true><<<512, 512, 0, stream>>>(Z, (size_t)P_ * H_, WT3, b3, Hb, P_, H_, H_);

    ln_head_k<<<P_ * A_ / 16, 256, 0, stream>>>(Hb, gamma, beta, W4, b4, out);
}